// Round 8
// baseline (1330.603 us; speedup 1.0000x reference)
//
#include <hip/hip_runtime.h>
#include <stdint.h>

typedef __attribute__((ext_vector_type(8))) __bf16 bf16x8;
typedef __attribute__((ext_vector_type(4))) float f32x4;

#define BM 256
#define BN 256
#define BKT 64   // K elems per tile; 2 K-halves of 32

__device__ __forceinline__ unsigned short f2bf_rne(float f) {
  unsigned int u = __builtin_bit_cast(unsigned int, f);
  u += 0x7FFFu + ((u >> 16) & 1u);
  return (unsigned short)(u >> 16);
}

__global__ void cvt_f32_to_bf16(const float* __restrict__ in,
                                unsigned short* __restrict__ out, long n4) {
  long stride = (long)gridDim.x * blockDim.x;
  for (long i = (long)blockIdx.x * blockDim.x + threadIdx.x; i < n4; i += stride) {
    float4 v = reinterpret_cast<const float4*>(in)[i];
    ushort4 o;
    o.x = f2bf_rne(v.x); o.y = f2bf_rne(v.y);
    o.z = f2bf_rne(v.z); o.w = f2bf_rne(v.w);
    reinterpret_cast<ushort4*>(out)[i] = o;
  }
}

__global__ void cvt_i32_to_bf16(const int* __restrict__ in,
                                unsigned short* __restrict__ out, long n4) {
  long stride = (long)gridDim.x * blockDim.x;
  for (long i = (long)blockIdx.x * blockDim.x + threadIdx.x; i < n4; i += stride) {
    int4 v = reinterpret_cast<const int4*>(in)[i];
    ushort4 o;
    o.x = f2bf_rne((float)v.x); o.y = f2bf_rne((float)v.y);
    o.z = f2bf_rne((float)v.z); o.w = f2bf_rne((float)v.w);
    reinterpret_cast<ushort4*>(out)[i] = o;
  }
}

#define GLDS16(g, l)                                                          \
  __builtin_amdgcn_global_load_lds(                                           \
      (const __attribute__((address_space(1))) unsigned int*)(g),             \
      (__attribute__((address_space(3))) unsigned int*)(l), 16, 0, 0)

// Inline-asm ds_read_b128: opaque to SIInsertWaitcnts. NO memory clobbers on
// any in-loop wait: a "memory"-clobbered asm is a may-read-LDS op, forcing
// the compiler to insert a hidden vmcnt(0) drain against pending LDS-DMA
// writes before it (this serialized R5-R7: ~2400 extra cyc/K-tile).
// Ordering is enforced by asm-volatile program order + sched_barrier(0).
typedef __attribute__((address_space(3))) const unsigned short lds_cu16;

template <int OFF>
__device__ __forceinline__ bf16x8 ldsb128(lds_cu16* p) {
  bf16x8 r;
  asm volatile("ds_read_b128 %0, %1 offset:%2" : "=v"(r) : "v"(p), "i"(OFF));
  return r;
}

__device__ __forceinline__ void ld4(lds_cu16* p, bf16x8 r[4]) {
  r[0] = ldsb128<0>(p);
  r[1] = ldsb128<1024>(p);
  r[2] = ldsb128<2048>(p);
  r[3] = ldsb128<3072>(p);
}

__device__ __forceinline__ void mfma16(const bf16x8 af[4], const bf16x8 bfr[4],
                                       f32x4 (*accRow)[4]) {
#pragma unroll
  for (int i = 0; i < 4; ++i)
#pragma unroll
    for (int j = 0; j < 4; ++j)
      accRow[i][j] = __builtin_amdgcn_mfma_f32_16x16x32_bf16(af[i], bfr[j],
                                                             accRow[i][j],
                                                             0, 0, 0);
}

#define BAR __builtin_amdgcn_s_barrier()
#define SCHEDB __builtin_amdgcn_sched_barrier(0)
// counted waits, NO clobbers (see above)
#define LGKM_0 asm volatile("s_waitcnt lgkmcnt(0)")
#define LGKM_4 asm volatile("s_waitcnt lgkmcnt(4)")
#define LGKM_8 asm volatile("s_waitcnt lgkmcnt(8)")
#define VMC_0 asm volatile("s_waitcnt vmcnt(0)")

// 256x256 GEMM, T2-swizzled, 1 barrier + 1 vmcnt(0) per K-tile (pre-barrier,
// one full tile of slack), counted-lgkm software pipeline inside the tile.
// DS ops retire in order, so counted lgkm waits gate exactly the group
// whose data is needed while later reads stay in flight:
//   issue b0,a0,a1 -> lgkm(4): b0,a0 ready -> MFMA g0
//   issue b1,a0'   -> lgkm(8): a1 ready    -> MFMA g1
//   issue a1'      -> lgkm(4): b1,a0' ready-> MFMA g2
//                     lgkm(0): a1' ready   -> MFMA g3
__global__ __launch_bounds__(512, 2) void gemm256_pipe(
    const unsigned short* __restrict__ A,   // [M][K] bf16
    const unsigned short* __restrict__ W,   // [N][K] bf16
    const float* __restrict__ scale,        // [N]
    const float* __restrict__ bias,         // [N]
    float* __restrict__ C,                  // [M][N] f32
    int M, int N, int K) {
  __shared__ __align__(16) unsigned short As[2][2][256 * 32];
  __shared__ __align__(16) unsigned short Bs[2][2][256 * 32];

  const int tid = threadIdx.x;
  const int lane = tid & 63;
  const int wv = tid >> 6;       // 0..7
  const int wm = wv >> 2;        // 0..1  (wave row: 128 rows)
  const int wn = wv & 3;         // 0..3  (wave col: 64 cols)

  const int nwg = gridDim.x;
  const int bid = blockIdx.x;
  const int wg = ((nwg & 7) == 0) ? ((bid & 7) * (nwg >> 3) + (bid >> 3)) : bid;
  const int mT = M / BM;
  const int bm = wg % mT;        // M-fast: neighbors share W panel
  const int bn = wg / mT;

  const long aRow0 = (long)bm * BM;
  const long wRow0 = (long)bn * BN;

  // staging: chunk c = 16 rows x 64B; lane l -> linear dest slot, inverse-
  // swizzled source column (logical slot (l&3)^((l>>3)&3)).
  const int c0 = wv, c1 = 8 + wv;
  const int sr0 = 16 * c0 + (lane >> 2);
  const int sr1 = 16 * c1 + (lane >> 2);
  const int sc = (((lane & 3) ^ ((lane >> 3) & 3))) * 8;
  const unsigned short* aS0 = A + (aRow0 + sr0) * (long)K + sc;
  const unsigned short* aS1 = A + (aRow0 + sr1) * (long)K + sc;
  const unsigned short* wS0 = W + (wRow0 + sr0) * (long)K + sc;
  const unsigned short* wS1 = W + (wRow0 + sr1) * (long)K + sc;
  const int d0 = c0 * 512 + lane * 8;
  const int d1 = c1 * 512 + lane * 8;

  // ds_read bases: row*32 + swizzled-slot*8 (XOR term lane-constant)
  const int sx = (lane >> 4) ^ ((lane >> 1) & 3);
  const int rdA = (wm * 128 + (lane & 15)) * 32 + sx * 8;
  const int rdB = (wn * 64 + (lane & 15)) * 32 + sx * 8;

  f32x4 acc[8][4] = {};
  bf16x8 b0[4], b1[4], a0[4], a1[4];

  const int nk = K / BKT;

  // prologue: stage tile 0 into buffer 0
  GLDS16(aS0, &As[0][0][d0]);
  GLDS16(aS1, &As[0][0][d1]);
  GLDS16(wS0, &Bs[0][0][d0]);
  GLDS16(wS1, &Bs[0][0][d1]);
  GLDS16(aS0 + 32, &As[0][1][d0]);
  GLDS16(aS1 + 32, &As[0][1][d1]);
  GLDS16(wS0 + 32, &Bs[0][1][d0]);
  GLDS16(wS1 + 32, &Bs[0][1][d1]);

#define TILE_BODY(CUR, NXT, KOFF)                                             \
  {                                                                           \
    SCHEDB;                                                                   \
    VMC_0; /* own CUR DMAs retired; issued a full tile ago -> cheap */        \
    BAR;   /* all waves drained pre-barrier -> CUR readable, NXT free */      \
    GLDS16(aS0 + (KOFF), &As[NXT][0][d0]);                                    \
    GLDS16(aS1 + (KOFF), &As[NXT][0][d1]);                                    \
    GLDS16(wS0 + (KOFF), &Bs[NXT][0][d0]);                                    \
    GLDS16(wS1 + (KOFF), &Bs[NXT][0][d1]);                                    \
    GLDS16(aS0 + (KOFF) + 32, &As[NXT][1][d0]);                               \
    GLDS16(aS1 + (KOFF) + 32, &As[NXT][1][d1]);                               \
    GLDS16(wS0 + (KOFF) + 32, &Bs[NXT][1][d0]);                               \
    GLDS16(wS1 + (KOFF) + 32, &Bs[NXT][1][d1]);                               \
    SCHEDB;                                                                   \
    ld4((lds_cu16*)&Bs[CUR][0][rdB], b0);                                     \
    ld4((lds_cu16*)&As[CUR][0][rdA], a0);                                     \
    ld4((lds_cu16*)&As[CUR][0][rdA + 2048], a1);                              \
    SCHEDB; LGKM_4; SCHEDB;                                                   \
    __builtin_amdgcn_s_setprio(1);                                            \
    mfma16(a0, b0, &acc[0]);                                                  \
    __builtin_amdgcn_s_setprio(0);                                            \
    SCHEDB;                                                                   \
    ld4((lds_cu16*)&Bs[CUR][1][rdB], b1);                                     \
    ld4((lds_cu16*)&As[CUR][1][rdA], a0);                                     \
    SCHEDB; LGKM_8; SCHEDB;                                                   \
    __builtin_amdgcn_s_setprio(1);                                            \
    mfma16(a1, b0, &acc[4]);                                                  \
    __builtin_amdgcn_s_setprio(0);                                            \
    SCHEDB;                                                                   \
    ld4((lds_cu16*)&As[CUR][1][rdA + 2048], a1);                              \
    SCHEDB; LGKM_4; SCHEDB;                                                   \
    __builtin_amdgcn_s_setprio(1);                                            \
    mfma16(a0, b1, &acc[0]);                                                  \
    __builtin_amdgcn_s_setprio(0);                                            \
    SCHEDB; LGKM_0; SCHEDB;                                                   \
    __builtin_amdgcn_s_setprio(1);                                            \
    mfma16(a1, b1, &acc[4]);                                                  \
    __builtin_amdgcn_s_setprio(0);                                            \
    SCHEDB;                                                                   \
  }

  for (int kt = 0; kt < nk; kt += 2) {
    const long ko1 = (long)(kt + 1) * BKT;                       // kt+1 < nk
    const long ko2 = (kt + 2 < nk) ? (long)(kt + 2) * BKT : 0;   // wrap ok
    TILE_BODY(0, 1, ko1);
    TILE_BODY(1, 0, ko2);
  }
#undef TILE_BODY

  // epilogue: C/D frag layout col=lane&15, row=(lane>>4)*4+v
  const long col0 = wRow0 + wn * 64 + (lane & 15);
  float scl[4], bs[4];
#pragma unroll
  for (int j = 0; j < 4; ++j) {
    scl[j] = scale[col0 + j * 16];
    bs[j] = bias[col0 + j * 16];
  }
  const long row0 = aRow0 + wm * 128 + ((lane >> 4) << 2);
#pragma unroll
  for (int i = 0; i < 8; ++i) {
#pragma unroll
    for (int v = 0; v < 4; ++v) {
      float* cp = C + (row0 + i * 16 + v) * (long)N + col0;
#pragma unroll
      for (int j = 0; j < 4; ++j)
        cp[j * 16] = acc[i][j][v] * scl[j] + bs[j];
    }
  }
}

// correctness-only fallback
__global__ void naive_w8a16(const float* __restrict__ inp,
                            const int* __restrict__ qw,
                            const float* __restrict__ scale,
                            const float* __restrict__ bias,
                            float* __restrict__ out, long M, long N, long K) {
  long idx = (long)blockIdx.x * blockDim.x + threadIdx.x;
  if (idx >= M * N) return;
  long col = idx % N, row = idx / N;
  const float* a = inp + row * K;
  const int* w = qw + col * K;
  float s = 0.f;
  for (long k = 0; k < K; k += 4) {
    float4 av = *reinterpret_cast<const float4*>(&a[k]);
    int4 wv = *reinterpret_cast<const int4*>(&w[k]);
    s += av.x * (float)wv.x + av.y * (float)wv.y + av.z * (float)wv.z +
         av.w * (float)wv.w;
  }
  out[idx] = s * scale[col] + bias[col];
}

extern "C" void kernel_launch(void* const* d_in, const int* in_sizes, int n_in,
                              void* d_out, int out_size, void* d_ws,
                              size_t ws_size, hipStream_t stream) {
  const float* inp = (const float*)d_in[0];   // [B,S,D_IN] f32
  const int* qw = (const int*)d_in[1];        // [D_OUT,D_IN] i32
  const float* scale = (const float*)d_in[2]; // [D_OUT]
  const float* bias = (const float*)d_in[3];  // [D_OUT]
  float* out = (float*)d_out;                 // [B,S,D_OUT] f32

  const long N = in_sizes[2];                 // 16384
  const long K = (long)in_sizes[1] / N;       // 4096
  const long M = (long)in_sizes[0] / K;       // 8192

  const size_t aBytes = (size_t)M * K * 2;
  const size_t wBytes = (size_t)N * K * 2;

  if (ws_size >= aBytes + wBytes && (M % BM) == 0 && (N % BN) == 0 &&
      (K % BKT) == 0 && (K / BKT) >= 2 && ((K / BKT) & 1) == 0) {
    unsigned short* Abf = (unsigned short*)d_ws;
    unsigned short* Wbf = (unsigned short*)((char*)d_ws + aBytes);
    cvt_f32_to_bf16<<<2048, 256, 0, stream>>>(inp, Abf, M * K / 4);
    cvt_i32_to_bf16<<<2048, 256, 0, stream>>>(qw, Wbf, N * K / 4);
    const int nwg = (int)((M / BM) * (N / BN));  // 2048
    gemm256_pipe<<<nwg, 512, 0, stream>>>(Abf, Wbf, scale, bias, out, (int)M,
                                          (int)N, (int)K);
  } else {
    long total = M * N;
    naive_w8a16<<<(int)((total + 255) / 256), 256, 0, stream>>>(
        inp, qw, scale, bias, out, M, N, K);
  }
}

// Round 9
// 1245.808 us; speedup vs baseline: 1.0681x; 1.0681x over previous
//
#include <hip/hip_runtime.h>
#include <stdint.h>

typedef __attribute__((ext_vector_type(8))) __bf16 bf16x8;
typedef __attribute__((ext_vector_type(4))) float f32x4;

#define BM 256
#define BN 256
#define BKT 32   // K elems per tile (one 32-KB {A,B} pair per buffer)

__device__ __forceinline__ unsigned short f2bf_rne(float f) {
  unsigned int u = __builtin_bit_cast(unsigned int, f);
  u += 0x7FFFu + ((u >> 16) & 1u);
  return (unsigned short)(u >> 16);
}

__global__ void cvt_f32_to_bf16(const float* __restrict__ in,
                                unsigned short* __restrict__ out, long n4) {
  long stride = (long)gridDim.x * blockDim.x;
  for (long i = (long)blockIdx.x * blockDim.x + threadIdx.x; i < n4; i += stride) {
    float4 v = reinterpret_cast<const float4*>(in)[i];
    ushort4 o;
    o.x = f2bf_rne(v.x); o.y = f2bf_rne(v.y);
    o.z = f2bf_rne(v.z); o.w = f2bf_rne(v.w);
    reinterpret_cast<ushort4*>(out)[i] = o;
  }
}

__global__ void cvt_i32_to_bf16(const int* __restrict__ in,
                                unsigned short* __restrict__ out, long n4) {
  long stride = (long)gridDim.x * blockDim.x;
  for (long i = (long)blockIdx.x * blockDim.x + threadIdx.x; i < n4; i += stride) {
    int4 v = reinterpret_cast<const int4*>(in)[i];
    ushort4 o;
    o.x = f2bf_rne((float)v.x); o.y = f2bf_rne((float)v.y);
    o.z = f2bf_rne((float)v.z); o.w = f2bf_rne((float)v.w);
    reinterpret_cast<ushort4*>(out)[i] = o;
  }
}

#define GLDS16(g, l)                                                          \
  __builtin_amdgcn_global_load_lds(                                           \
      (const __attribute__((address_space(1))) unsigned int*)(g),             \
      (__attribute__((address_space(3))) unsigned int*)(l), 16, 0, 0)

// Inline-asm ds_read_b128 (opaque to SIInsertWaitcnts; no clobbers anywhere
// in-loop so the compiler cannot insert hidden vmcnt(0) drains). rule #18:
// every manual wait is followed by sched_barrier(0).
typedef __attribute__((address_space(3))) const unsigned short lds_cu16;

template <int OFF>
__device__ __forceinline__ bf16x8 ldsb128(lds_cu16* p) {
  bf16x8 r;
  asm volatile("ds_read_b128 %0, %1 offset:%2" : "=v"(r) : "v"(p), "i"(OFF));
  return r;
}

__device__ __forceinline__ void ld4(lds_cu16* p, bf16x8 r[4]) {
  r[0] = ldsb128<0>(p);
  r[1] = ldsb128<1024>(p);
  r[2] = ldsb128<2048>(p);
  r[3] = ldsb128<3072>(p);
}

__device__ __forceinline__ void mfma16(const bf16x8 af[4], const bf16x8 bfr[4],
                                       f32x4 (*accRow)[4]) {
#pragma unroll
  for (int i = 0; i < 4; ++i)
#pragma unroll
    for (int j = 0; j < 4; ++j)
      accRow[i][j] = __builtin_amdgcn_mfma_f32_16x16x32_bf16(af[i], bfr[j],
                                                             accRow[i][j],
                                                             0, 0, 0);
}

#define BAR __builtin_amdgcn_s_barrier()
#define SCHEDB __builtin_amdgcn_sched_barrier(0)
#define LGKM_0 asm volatile("s_waitcnt lgkmcnt(0)")
#define LGKM_4 asm volatile("s_waitcnt lgkmcnt(4)")
#define VMC_4 asm volatile("s_waitcnt vmcnt(4)")

// 256x256 GEMM, T2-swizzled, QUAD-buffered LDS with 2-tile DMA prefetch.
// T4 discipline: the per-wave gload_lds queue NEVER drains - vmcnt(4) at
// tile top retires only tile kt's 4 oldest loads (kt+1's 4 stay in flight),
// then kt+2's 4 issue immediately. Queue depth oscillates 4<->8, so the DMA
// engine streams continuously instead of idling at a vmcnt(0) wall (the
// R5-R8 plateau: ~2900 cyc/tile of exposed DMA drain). WAR safe: buffer
// (kt+2)&3 was last read in tile kt-2, two barriers before its rewrite.
__global__ __launch_bounds__(512, 2) void gemm256_q4(
    const unsigned short* __restrict__ A,   // [M][K] bf16
    const unsigned short* __restrict__ W,   // [N][K] bf16
    const float* __restrict__ scale,        // [N]
    const float* __restrict__ bias,         // [N]
    float* __restrict__ C,                  // [M][N] f32
    int M, int N, int K) {
  __shared__ __align__(16) unsigned short As[4][256 * 32];  // 64 KiB
  __shared__ __align__(16) unsigned short Bs[4][256 * 32];  // 64 KiB

  const int tid = threadIdx.x;
  const int lane = tid & 63;
  const int wv = tid >> 6;       // 0..7
  const int wm = wv >> 2;        // 0..1  (wave row: 128 rows)
  const int wn = wv & 3;         // 0..3  (wave col: 64 cols)

  const int nwg = gridDim.x;
  const int bid = blockIdx.x;
  const int wg = ((nwg & 7) == 0) ? ((bid & 7) * (nwg >> 3) + (bid >> 3)) : bid;
  const int mT = M / BM;
  const int bm = wg % mT;        // M-fast: neighbors share W panel
  const int bn = wg / mT;

  const long aRow0 = (long)bm * BM;
  const long wRow0 = (long)bn * BN;

  // staging: chunk c = 16 rows x 64B; lane l -> linear dest slot, inverse-
  // swizzled source column (logical slot (l&3)^((l>>3)&3)).
  const int c0 = wv, c1 = 8 + wv;
  const int sr0 = 16 * c0 + (lane >> 2);
  const int sr1 = 16 * c1 + (lane >> 2);
  const int sc = (((lane & 3) ^ ((lane >> 3) & 3))) * 8;
  const unsigned short* aS0 = A + (aRow0 + sr0) * (long)K + sc;
  const unsigned short* aS1 = A + (aRow0 + sr1) * (long)K + sc;
  const unsigned short* wS0 = W + (wRow0 + sr0) * (long)K + sc;
  const unsigned short* wS1 = W + (wRow0 + sr1) * (long)K + sc;
  const int d0 = c0 * 512 + lane * 8;
  const int d1 = c1 * 512 + lane * 8;

  // ds_read bases: row*32 + swizzled-slot*8 (XOR term lane-constant)
  const int sx = (lane >> 4) ^ ((lane >> 1) & 3);
  const int rdA = (wm * 128 + (lane & 15)) * 32 + sx * 8;
  const int rdB = (wn * 64 + (lane & 15)) * 32 + sx * 8;

  f32x4 acc[8][4] = {};
  bf16x8 bfr[4], a0[4], a1[4];

  const int nk = K / BKT;   // 128 (guarded % 4 == 0)

  // prologue: stage tile 0 -> buf0, tile 1 -> buf1 (8 loads in flight)
  GLDS16(aS0, &As[0][d0]);
  GLDS16(aS1, &As[0][d1]);
  GLDS16(wS0, &Bs[0][d0]);
  GLDS16(wS1, &Bs[0][d1]);
  GLDS16(aS0 + BKT, &As[1][d0]);
  GLDS16(aS1 + BKT, &As[1][d1]);
  GLDS16(wS0 + BKT, &Bs[1][d0]);
  GLDS16(wS1 + BKT, &Bs[1][d1]);

#define TILE_BODY(CUR, STG, KOFF)                                             \
  {                                                                           \
    SCHEDB;                                                                   \
    VMC_4; /* tile CUR's 4 oldest retired; next tile's 4 stay in flight */    \
    BAR;   /* publish CUR's DMA writes; buf STG's readers long done */        \
    GLDS16(aS0 + (KOFF), &As[STG][d0]);                                       \
    GLDS16(aS1 + (KOFF), &As[STG][d1]);                                       \
    GLDS16(wS0 + (KOFF), &Bs[STG][d0]);                                       \
    GLDS16(wS1 + (KOFF), &Bs[STG][d1]);                                       \
    SCHEDB;                                                                   \
    ld4((lds_cu16*)&Bs[CUR][rdB], bfr);                                       \
    ld4((lds_cu16*)&As[CUR][rdA], a0);                                        \
    ld4((lds_cu16*)&As[CUR][rdA + 2048], a1);                                 \
    SCHEDB; LGKM_4; SCHEDB; /* bfr,a0 ready; a1 in flight */                  \
    __builtin_amdgcn_s_setprio(1);                                            \
    mfma16(a0, bfr, &acc[0]);                                                 \
    __builtin_amdgcn_s_setprio(0);                                            \
    SCHEDB; LGKM_0; SCHEDB; /* a1 ready */                                    \
    __builtin_amdgcn_s_setprio(1);                                            \
    mfma16(a1, bfr, &acc[4]);                                                 \
    __builtin_amdgcn_s_setprio(0);                                            \
    SCHEDB;                                                                   \
  }

  for (int kt = 0; kt < nk; kt += 4) {
    const long ko2 = (long)(kt + 2) * BKT;                        // < nk
    const long ko3 = (long)(kt + 3) * BKT;                        // < nk
    const long ko4 = (kt + 4 < nk) ? (long)(kt + 4) * BKT : 0;    // wrap ok
    const long ko5 = (kt + 5 < nk) ? (long)(kt + 5) * BKT : 0;    // wrap ok
    TILE_BODY(0, 2, ko2);
    TILE_BODY(1, 3, ko3);
    TILE_BODY(2, 0, ko4);
    TILE_BODY(3, 1, ko5);
  }
#undef TILE_BODY

  // epilogue: C/D frag layout col=lane&15, row=(lane>>4)*4+v
  const long col0 = wRow0 + wn * 64 + (lane & 15);
  float scl[4], bs[4];
#pragma unroll
  for (int j = 0; j < 4; ++j) {
    scl[j] = scale[col0 + j * 16];
    bs[j] = bias[col0 + j * 16];
  }
  const long row0 = aRow0 + wm * 128 + ((lane >> 4) << 2);
#pragma unroll
  for (int i = 0; i < 8; ++i) {
#pragma unroll
    for (int v = 0; v < 4; ++v) {
      float* cp = C + (row0 + i * 16 + v) * (long)N + col0;
#pragma unroll
      for (int j = 0; j < 4; ++j)
        cp[j * 16] = acc[i][j][v] * scl[j] + bs[j];
    }
  }
}

// correctness-only fallback
__global__ void naive_w8a16(const float* __restrict__ inp,
                            const int* __restrict__ qw,
                            const float* __restrict__ scale,
                            const float* __restrict__ bias,
                            float* __restrict__ out, long M, long N, long K) {
  long idx = (long)blockIdx.x * blockDim.x + threadIdx.x;
  if (idx >= M * N) return;
  long col = idx % N, row = idx / N;
  const float* a = inp + row * K;
  const int* w = qw + col * K;
  float s = 0.f;
  for (long k = 0; k < K; k += 4) {
    float4 av = *reinterpret_cast<const float4*>(&a[k]);
    int4 wv = *reinterpret_cast<const int4*>(&w[k]);
    s += av.x * (float)wv.x + av.y * (float)wv.y + av.z * (float)wv.z +
         av.w * (float)wv.w;
  }
  out[idx] = s * scale[col] + bias[col];
}

extern "C" void kernel_launch(void* const* d_in, const int* in_sizes, int n_in,
                              void* d_out, int out_size, void* d_ws,
                              size_t ws_size, hipStream_t stream) {
  const float* inp = (const float*)d_in[0];   // [B,S,D_IN] f32
  const int* qw = (const int*)d_in[1];        // [D_OUT,D_IN] i32
  const float* scale = (const float*)d_in[2]; // [D_OUT]
  const float* bias = (const float*)d_in[3];  // [D_OUT]
  float* out = (float*)d_out;                 // [B,S,D_OUT] f32

  const long N = in_sizes[2];                 // 16384
  const long K = (long)in_sizes[1] / N;       // 4096
  const long M = (long)in_sizes[0] / K;       // 8192

  const size_t aBytes = (size_t)M * K * 2;
  const size_t wBytes = (size_t)N * K * 2;
  const long nk = K / BKT;

  if (ws_size >= aBytes + wBytes && (M % BM) == 0 && (N % BN) == 0 &&
      (K % BKT) == 0 && nk >= 8 && (nk % 4) == 0) {
    unsigned short* Abf = (unsigned short*)d_ws;
    unsigned short* Wbf = (unsigned short*)((char*)d_ws + aBytes);
    cvt_f32_to_bf16<<<2048, 256, 0, stream>>>(inp, Abf, M * K / 4);
    cvt_i32_to_bf16<<<2048, 256, 0, stream>>>(qw, Wbf, N * K / 4);
    const int nwg = (int)((M / BM) * (N / BN));  // 2048
    gemm256_q4<<<nwg, 512, 0, stream>>>(Abf, Wbf, scale, bias, out, (int)M,
                                        (int)N, (int)K);
  } else {
    long total = M * N;
    naive_w8a16<<<(int)((total + 255) / 256), 256, 0, stream>>>(
        inp, qw, scale, bias, out, M, N, K);
  }
}